// Round 2
// baseline (6298.383 us; speedup 1.0000x reference)
//
#include <hip/hip_runtime.h>
#include <hip/hip_bf16.h>

#define NL  3
#define NB  128
#define NT  256
#define NH  512
#define NH3 1536
#define NBH (NB*NH)      // 65536
#define NM  (NB*NT)      // 32768

typedef __bf16 bf16x8 __attribute__((ext_vector_type(8)));
typedef float  floatx4 __attribute__((ext_vector_type(4)));
typedef __hip_bfloat16 bf16;

__device__ __forceinline__ floatx4 mfma16(bf16x8 a, bf16x8 b, floatx4 c) {
  return __builtin_amdgcn_mfma_f32_16x16x32_bf16(a, b, c, 0, 0, 0);
}
__device__ __forceinline__ void gload16(const void* g, void* l) {
  __builtin_amdgcn_global_load_lds(
      (const __attribute__((address_space(1))) unsigned int*)g,
      (__attribute__((address_space(3))) unsigned int*)l, 16, 0, 0);
}
__device__ __forceinline__ float fsig(float x)  { return 1.0f / (1.0f + __expf(-x)); }
__device__ __forceinline__ float ftanh(float x) { return 2.0f / (1.0f + __expf(-2.0f*x)) - 1.0f; }

// ---------- transpose + cvt weights: fp32 [NL][NH][NH3] -> bf16 [NL][NH3][NH] ----------
__global__ void transpose_cvt_kernel(const float* __restrict__ in, bf16* __restrict__ out) {
  __shared__ float tile[32][33];
  int l = blockIdx.z;
  int n0 = blockIdx.x * 32, k0 = blockIdx.y * 32;
  const float* src = in + (size_t)l * NH * NH3;
  bf16* dst = out + (size_t)l * NH3 * NH;
  int tx = threadIdx.x, ty = threadIdx.y;    // 32 x 8
#pragma unroll
  for (int i = 0; i < 4; i++)
    tile[ty + 8*i][tx] = src[(size_t)(k0 + ty + 8*i) * NH3 + n0 + tx];
  __syncthreads();
#pragma unroll
  for (int i = 0; i < 4; i++)
    dst[(size_t)(n0 + ty + 8*i) * NH + k0 + tx] = __float2bfloat16(tile[tx][ty + 8*i]);
}

// ---------- elementwise fp32 -> bf16 (x input) ----------
__global__ void cvt_x_kernel(const float* __restrict__ in, bf16* __restrict__ out) {
  size_t i = (size_t)blockIdx.x * blockDim.x + threadIdx.x;
  float4 v = ((const float4*)in)[i];
  bf16 o0 = __float2bfloat16(v.x), o1 = __float2bfloat16(v.y);
  bf16 o2 = __float2bfloat16(v.z), o3 = __float2bfloat16(v.w);
  ushort4 pk;
  __builtin_memcpy(&pk.x, &o0, 2); __builtin_memcpy(&pk.y, &o1, 2);
  __builtin_memcpy(&pk.z, &o2, 2); __builtin_memcpy(&pk.w, &o3, 2);
  ((ushort4*)out)[i] = pk;
}

// ---------- xp GEMM: C[m][n] = A[m,:512] @ Bt[n,:512]^T + bias[n], bf16 out ----------
// a_mode==0: A row m sourced from x[b=m%128][t=m/128]  (layer-0 [B][T][H] input)
// a_mode==1: A row m at m*NH (slot-major seq)
__global__ void __launch_bounds__(256, 2) gemm_xp_kernel(
    const bf16* __restrict__ A, const bf16* __restrict__ Bt,
    const float* __restrict__ bias, bf16* __restrict__ C, int a_mode)
{
  __shared__ char alds[16384];   // fragment order: [kt(2)][mtile(8)][lane(64)]*16B
  __shared__ char blds[16384];
  int tid = threadIdx.x;
  int lane = tid & 63, w = tid >> 6;       // 4 waves
  int mblk = blockIdx.x, nblk = blockIdx.y;
  int wm = w >> 1, wn = w & 1;             // 2x2 wave grid, 64x64 each
  int klane = (lane >> 4) * 8;
  int r0 = 2*w*16 + (lane & 15);           // staged rows: mtiles {2w, 2w+1}
  size_t arow0, arow1;
  if (a_mode == 0) {
    arow0 = ((size_t)r0 * NT + mblk) * NH;
    arow1 = ((size_t)(r0 + 16) * NT + mblk) * NH;
  } else {
    arow0 = (size_t)(mblk*128 + r0) * NH;
    arow1 = arow0 + (size_t)16 * NH;
  }
  size_t brow0 = (size_t)(nblk*128 + 2*w*16 + (lane & 15)) * NH;
  size_t brow1 = brow0 + (size_t)16 * NH;

  floatx4 acc[4][4];
#pragma unroll
  for (int i = 0; i < 4; i++)
#pragma unroll
    for (int j = 0; j < 4; j++) acc[i][j] = (floatx4){0.f, 0.f, 0.f, 0.f};

  for (int kk = 0; kk < 8; kk++) {         // K = 512, BK = 64
    int kb = kk*64 + klane;
#pragma unroll
    for (int kt = 0; kt < 2; kt++) {
      int kg = kb + kt*32;
      gload16(A  + arow0 + kg, alds + (kt*8 + 2*w    ) * 1024);
      gload16(A  + arow1 + kg, alds + (kt*8 + 2*w + 1) * 1024);
      gload16(Bt + brow0 + kg, blds + (kt*8 + 2*w    ) * 1024);
      gload16(Bt + brow1 + kg, blds + (kt*8 + 2*w + 1) * 1024);
    }
    __syncthreads();                       // drains vmcnt -> LDS tiles ready
#pragma unroll
    for (int kt = 0; kt < 2; kt++) {
      bf16x8 af[4], bfr[4];
#pragma unroll
      for (int i = 0; i < 4; i++) af[i]  = *(const bf16x8*)(alds + ((kt*8 + wm*4 + i)*64 + lane)*16);
#pragma unroll
      for (int j = 0; j < 4; j++) bfr[j] = *(const bf16x8*)(blds + ((kt*8 + wn*4 + j)*64 + lane)*16);
#pragma unroll
      for (int i = 0; i < 4; i++)
#pragma unroll
        for (int j = 0; j < 4; j++)
          acc[i][j] = mfma16(af[i], bfr[j], acc[i][j]);
    }
    __syncthreads();
  }
  int cl = lane & 15, rbase = (lane >> 4) * 4;   // C/D: col=lane&15, row=(lane>>4)*4+reg
#pragma unroll
  for (int i = 0; i < 4; i++) {
    int gm = mblk*128 + wm*64 + i*16 + rbase;
#pragma unroll
    for (int j = 0; j < 4; j++) {
      int gn = nblk*128 + wn*64 + j*16 + cl;
      float bv = bias[gn];
#pragma unroll
      for (int r = 0; r < 4; r++)
        C[(size_t)(gm + r) * NH3 + gn] = __float2bfloat16(acc[i][j][r] + bv);
    }
  }
}

// ---------- persistent GRU scan: 128 blocks = 8 batch-groups x 16 col-blocks ----------
// blockIdx = c*8 + g. fp32 carry lives in LDS (each block owns rows bb0..+15 x cols j0..+31).
__global__ void __launch_bounds__(384) gru_scan_kernel(
    const bf16*  __restrict__ wuT,     // [NH3][NH] bf16 (this layer)
    const float* __restrict__ br,      // [NH3] recurrent bias
    const bf16*  __restrict__ xp,      // [NM][NH3] bf16, row = t*NB + b
    const bf16*  __restrict__ h0bf,    // [B][H] bf16 h0, or null -> zeros
    bf16*        __restrict__ seq,     // [NT+1][B][H] bf16 (slots 1..NT written)
    const float* __restrict__ hf0,     // [B][H] fp32 h0, or null -> zeros
    float*       __restrict__ outBTH,  // layer2: d_out [B][T][H] fp32; else null
    float*       __restrict__ hfinal,  // [B][H] fp32 final-state sink (always set)
    unsigned*    __restrict__ cnt, unsigned tgtbase)
{
  __shared__ char  h_l[16384];         // A-fragments: [kt(16)][lane(64)]*16B
  __shared__ float rec_l[16 * 100];    // [row][col(96 pad->100)]
  __shared__ float hcur[512];          // fp32 carry [row(16)][j(32)]
  __shared__ int   deadflag;
  int tid = threadIdx.x, lane = tid & 63, w = tid >> 6;   // 6 waves
  int g = blockIdx.x & 7, c = blockIdx.x >> 3;
  int bb0 = g * 16, j0 = c * 32;
  int klane = (lane >> 4) * 8;
  if (tid == 0) deadflag = 0;

  // init fp32 carry
  for (int idx = tid; idx < 512; idx += 384) {
    int row = idx >> 5, j = idx & 31;
    hcur[idx] = hf0 ? hf0[(size_t)(bb0 + row) * NH + j0 + j] : 0.0f;
  }

  // hoist this wave's Wu B-fragments (loop-invariant): 16 x bf16x8 = 64 VGPR
  bf16x8 wfrag[16];
  {
    int cl = w*16 + (lane & 15);                 // local rec col 0..95
    int ng = (cl >> 5) * NH + j0 + (cl & 31);    // global rec col (z/r/h thirds)
    const bf16* wrow = wuT + (size_t)ng * NH + klane;
#pragma unroll
    for (int kt = 0; kt < 16; kt++) wfrag[kt] = *(const bf16x8*)(wrow + kt*32);
  }
  __syncthreads();

  for (int t = 0; t < NT; t++) {
    // stage h_prev [16 x 512] bf16 into LDS in A-fragment order
    const bf16* hsrc = (t == 0) ? h0bf : (seq + (size_t)t * NBH);
    bool zero = (t == 0) && (h0bf == nullptr);
    for (int task = tid; task < 1024; task += 384) {
      int ln = task & 63, kt = task >> 6;
      int4 v = {0, 0, 0, 0};
      if (!zero) {
        int row = ln & 15, kg = kt*32 + ((ln >> 4) * 8);
        v = *(const int4*)(hsrc + (size_t)(bb0 + row) * NH + kg);
      }
      *(int4*)(h_l + (kt*64 + ln) * 16) = v;
    }
    __syncthreads();

    // rec tile: [16 x 16] per wave, K=512, 2-acc ILP
    floatx4 a0 = (floatx4){0,0,0,0}, a1 = (floatx4){0,0,0,0};
#pragma unroll
    for (int kt = 0; kt < 16; kt += 2) {
      bf16x8 hA = *(const bf16x8*)(h_l + ( kt   *64 + lane) * 16);
      bf16x8 hB = *(const bf16x8*)(h_l + ((kt+1)*64 + lane) * 16);
      a0 = mfma16(hA, wfrag[kt],   a0);
      a1 = mfma16(hB, wfrag[kt+1], a1);
    }
    {
      int cl = w*16 + (lane & 15);
      int rr0 = (lane >> 4) * 4;
#pragma unroll
      for (int r = 0; r < 4; r++)
        rec_l[(rr0 + r)*100 + cl] = a0[r] + a1[r];
    }
    __syncthreads();

    // gates: 512 elements (16 rows x 32 j), fp32 carry in LDS
    for (int idx = tid; idx < 512; idx += 384) {
      int row = idx >> 5, j = idx & 31;
      int bb = bb0 + row, jg = j0 + j;
      size_t xoff = ((size_t)t * NB + bb) * NH3 + jg;
      float xz = __bfloat162float(xp[xoff]);
      float xr = __bfloat162float(xp[xoff + 512]);
      float xh = __bfloat162float(xp[xoff + 1024]);
      float rz = rec_l[row*100 + j]      + br[jg];
      float rr = rec_l[row*100 + 32 + j] + br[512 + jg];
      float rh = rec_l[row*100 + 64 + j] + br[1024 + jg];
      float hp = hcur[idx];
      float z  = fsig(xz + rz);
      float r  = fsig(xr + rr);
      float hh = ftanh(xh + r * rh);
      float hn = z * hp + (1.0f - z) * hh;
      hcur[idx] = hn;
      if (outBTH) outBTH[((size_t)bb * NT + t) * NH + jg] = hn;
      if (t == NT-1) hfinal[(size_t)bb * NH + jg] = hn;
      seq[(size_t)(t+1) * NBH + (size_t)bb * NH + jg] = __float2bfloat16(hn);
    }
    __syncthreads();   // vmcnt drained (compiler emits full waitcnt before barrier)

    // per-group barrier (monotonic counter, agent scope); skip after last step
    if (t < NT-1) {
      if (tid == 0) {
        __threadfence();
        __hip_atomic_fetch_add(cnt + g, 1u, __ATOMIC_RELEASE, __HIP_MEMORY_SCOPE_AGENT);
        unsigned tgt = tgtbase + 16u * (unsigned)(t + 1);
        long spins = 0;
        while (__hip_atomic_load(cnt + g, __ATOMIC_RELAXED, __HIP_MEMORY_SCOPE_AGENT) < tgt) {
          __builtin_amdgcn_s_sleep(1);
          if (++spins > (1L << 22)) { deadflag = 1; break; }   // fail loud, not forever
        }
        __threadfence();
      }
      __syncthreads();
      if (deadflag) return;
    }
  }
}

extern "C" void kernel_launch(void* const* d_in, const int* in_sizes, int n_in,
                              void* d_out, int out_size, void* d_ws, size_t ws_size,
                              hipStream_t stream) {
  const float* x   = (const float*)d_in[0];
  const float* wk  = (const float*)d_in[1];
  const float* wu  = (const float*)d_in[2];
  const float* bis = (const float*)d_in[3];
  float* out = (float*)d_out;

  // workspace layout (bytes):
  //   wkT   [3][1536][512] bf16      @ 0          (4,718,592)
  //   wuT   [3][1536][512] bf16      @ 4,718,592  (4,718,592)
  //   xp    [32768][1536] bf16       @ 9,437,184  (100,663,296)
  //   seq   [257][128][512] bf16     @ 110,100,480 (33,685,504)  (xb aliases base)
  //   hlast [128][512] fp32          @ 143,785,984 (262,144)
  //   cnt   8 x u32 (+pad)           @ 144,048,128 (64)
  // total 144,048,192 B (~137.4 MiB)
  const size_t REQ = 144048192;
  if (ws_size < REQ) {   // diagnosable failure instead of a memory-fault core dump
    hipMemsetAsync(d_out, 0, (size_t)out_size * 4, stream);
    return;
  }
  char* ws = (char*)d_ws;
  bf16*  wkT   = (bf16*)(ws);
  bf16*  wuT   = (bf16*)(ws + 4718592);
  bf16*  xp    = (bf16*)(ws + 9437184);
  bf16*  seq   = (bf16*)(ws + 110100480);
  bf16*  xb    = seq;                          // alias: dead after layer-0 GEMM
  float* hlast = (float*)(ws + 143785984);
  unsigned* cnt = (unsigned*)(ws + 144048128);

  hipMemsetAsync(cnt, 0, 64, stream);
  transpose_cvt_kernel<<<dim3(48,16,3), dim3(32,8), 0, stream>>>(wk, wkT);
  transpose_cvt_kernel<<<dim3(48,16,3), dim3(32,8), 0, stream>>>(wu, wuT);
  cvt_x_kernel<<<(NM*NH/4)/256, 256, 0, stream>>>(x, xb);

  const size_t WS = (size_t)NH3 * NH;   // per-layer weight stride

  // layer 0
  gemm_xp_kernel<<<dim3(256,12), 256, 0, stream>>>(xb, wkT, bis + 0*2*NH3, xp, 0);
  gru_scan_kernel<<<128, 384, 0, stream>>>(wuT, bis + 0*2*NH3 + NH3, xp,
      nullptr, seq, nullptr, nullptr, hlast, cnt, 0u);
  // layer 1
  gemm_xp_kernel<<<dim3(256,12), 256, 0, stream>>>(seq + NBH, wkT + WS, bis + 1*2*NH3, xp, 1);
  gru_scan_kernel<<<128, 384, 0, stream>>>(wuT + WS, bis + 1*2*NH3 + NH3, xp,
      seq + (size_t)NT * NBH, seq, hlast, nullptr, hlast, cnt, 4080u);
  // layer 2: fp32 chain straight into d_out [B][T][H]; final state to d_out tail
  gemm_xp_kernel<<<dim3(256,12), 256, 0, stream>>>(seq + NBH, wkT + 2*WS, bis + 2*2*NH3, xp, 1);
  gru_scan_kernel<<<128, 384, 0, stream>>>(wuT + 2*WS, bis + 2*2*NH3 + NH3, xp,
      seq + (size_t)NT * NBH, seq, hlast, out, out + (size_t)NT * NBH, cnt, 8160u);

  (void)in_sizes; (void)n_in; (void)out_size; (void)ws_size;
}

// Round 3
// 4129.668 us; speedup vs baseline: 1.5252x; 1.5252x over previous
//
#include <hip/hip_runtime.h>
#include <hip/hip_bf16.h>

#define NL  3
#define NB  128
#define NT  256
#define NH  512
#define NH3 1536
#define NBH (NB*NH)      // 65536
#define NM  (NB*NT)      // 32768

typedef __bf16 bf16x8 __attribute__((ext_vector_type(8)));
typedef unsigned short u16x8 __attribute__((ext_vector_type(8)));
typedef float  floatx4 __attribute__((ext_vector_type(4)));
typedef __hip_bfloat16 bf16;

__device__ __forceinline__ floatx4 mfma16(bf16x8 a, bf16x8 b, floatx4 c) {
  return __builtin_amdgcn_mfma_f32_16x16x32_bf16(a, b, c, 0, 0, 0);
}
__device__ __forceinline__ void gload16(const void* g, void* l) {
  __builtin_amdgcn_global_load_lds(
      (const __attribute__((address_space(1))) unsigned int*)g,
      (__attribute__((address_space(3))) unsigned int*)l, 16, 0, 0);
}
__device__ __forceinline__ float fsig(float x)  { return 1.0f / (1.0f + __expf(-x)); }
__device__ __forceinline__ float ftanh(float x) { return 2.0f / (1.0f + __expf(-2.0f*x)) - 1.0f; }
__device__ __forceinline__ float b2f(unsigned short u) {
  unsigned v = (unsigned)u << 16; float f; __builtin_memcpy(&f, &v, 4); return f;
}
__device__ __forceinline__ unsigned short f2b(float f) {
  bf16 h = __float2bfloat16(f); unsigned short u; __builtin_memcpy(&u, &h, 2); return u;
}

// ---------- transpose + cvt weights: fp32 [NL][NH][NH3] -> bf16 [NL][NH3][NH] ----------
__global__ void transpose_cvt_kernel(const float* __restrict__ in, bf16* __restrict__ out) {
  __shared__ float tile[32][33];
  int l = blockIdx.z;
  int n0 = blockIdx.x * 32, k0 = blockIdx.y * 32;
  const float* src = in + (size_t)l * NH * NH3;
  bf16* dst = out + (size_t)l * NH3 * NH;
  int tx = threadIdx.x, ty = threadIdx.y;    // 32 x 8
#pragma unroll
  for (int i = 0; i < 4; i++)
    tile[ty + 8*i][tx] = src[(size_t)(k0 + ty + 8*i) * NH3 + n0 + tx];
  __syncthreads();
#pragma unroll
  for (int i = 0; i < 4; i++)
    dst[(size_t)(n0 + ty + 8*i) * NH + k0 + tx] = __float2bfloat16(tile[tx][ty + 8*i]);
}

// ---------- elementwise fp32 -> bf16 (x input) ----------
__global__ void cvt_x_kernel(const float* __restrict__ in, bf16* __restrict__ out) {
  size_t i = (size_t)blockIdx.x * blockDim.x + threadIdx.x;
  float4 v = ((const float4*)in)[i];
  ushort4 pk;
  pk.x = f2b(v.x); pk.y = f2b(v.y); pk.z = f2b(v.z); pk.w = f2b(v.w);
  ((ushort4*)out)[i] = pk;
}

// ---------- xp GEMM: C[m][n] = A[m,:512] @ Bt[n,:512]^T + bias[n], bf16 out ----------
__global__ void __launch_bounds__(256, 2) gemm_xp_kernel(
    const bf16* __restrict__ A, const bf16* __restrict__ Bt,
    const float* __restrict__ bias, bf16* __restrict__ C, int a_mode)
{
  __shared__ char alds[16384];   // fragment order: [kt(2)][mtile(8)][lane(64)]*16B
  __shared__ char blds[16384];
  int tid = threadIdx.x;
  int lane = tid & 63, w = tid >> 6;       // 4 waves
  int mblk = blockIdx.x, nblk = blockIdx.y;
  int wm = w >> 1, wn = w & 1;             // 2x2 wave grid, 64x64 each
  int klane = (lane >> 4) * 8;
  int r0 = 2*w*16 + (lane & 15);           // staged rows: mtiles {2w, 2w+1}
  size_t arow0, arow1;
  if (a_mode == 0) {
    arow0 = ((size_t)r0 * NT + mblk) * NH;
    arow1 = ((size_t)(r0 + 16) * NT + mblk) * NH;
  } else {
    arow0 = (size_t)(mblk*128 + r0) * NH;
    arow1 = arow0 + (size_t)16 * NH;
  }
  size_t brow0 = (size_t)(nblk*128 + 2*w*16 + (lane & 15)) * NH;
  size_t brow1 = brow0 + (size_t)16 * NH;

  floatx4 acc[4][4];
#pragma unroll
  for (int i = 0; i < 4; i++)
#pragma unroll
    for (int j = 0; j < 4; j++) acc[i][j] = (floatx4){0.f, 0.f, 0.f, 0.f};

  for (int kk = 0; kk < 8; kk++) {         // K = 512, BK = 64
    int kb = kk*64 + klane;
#pragma unroll
    for (int kt = 0; kt < 2; kt++) {
      int kg = kb + kt*32;
      gload16(A  + arow0 + kg, alds + (kt*8 + 2*w    ) * 1024);
      gload16(A  + arow1 + kg, alds + (kt*8 + 2*w + 1) * 1024);
      gload16(Bt + brow0 + kg, blds + (kt*8 + 2*w    ) * 1024);
      gload16(Bt + brow1 + kg, blds + (kt*8 + 2*w + 1) * 1024);
    }
    __syncthreads();
#pragma unroll
    for (int kt = 0; kt < 2; kt++) {
      bf16x8 af[4], bfr[4];
#pragma unroll
      for (int i = 0; i < 4; i++) af[i]  = *(const bf16x8*)(alds + ((kt*8 + wm*4 + i)*64 + lane)*16);
#pragma unroll
      for (int j = 0; j < 4; j++) bfr[j] = *(const bf16x8*)(blds + ((kt*8 + wn*4 + j)*64 + lane)*16);
#pragma unroll
      for (int i = 0; i < 4; i++)
#pragma unroll
        for (int j = 0; j < 4; j++)
          acc[i][j] = mfma16(af[i], bfr[j], acc[i][j]);
    }
    __syncthreads();
  }
  int cl = lane & 15, rbase = (lane >> 4) * 4;   // C/D: col=lane&15, row=(lane>>4)*4+reg
#pragma unroll
  for (int i = 0; i < 4; i++) {
    int gm = mblk*128 + wm*64 + i*16 + rbase;
#pragma unroll
    for (int j = 0; j < 4; j++) {
      int gn = nblk*128 + wn*64 + j*16 + cl;
      float bv = bias[gn];
#pragma unroll
      for (int r = 0; r < 4; r++)
        C[(size_t)(gm + r) * NH3 + gn] = __float2bfloat16(acc[i][j][r] + bv);
    }
  }
}

// ---------- persistent GRU scan: 32 blocks = 8 batch-groups x 4 col-blocks ----------
// Block = 256 threads (4 waves, 1/SIMD, <=512 VGPR). Each block: 16 rows x 384 rec-cols
// (= 128 h-cols x 3 gates). Wu slice lives in registers (384 VGPR/wave).
// Cross-block h exchange via device-coherent relaxed atomics — NO fences, no L2 flush.
__global__ void __launch_bounds__(256, 1) gru_scan_kernel(
    const bf16*  __restrict__ wuT,     // [NH3][NH] bf16 (this layer)
    const float* __restrict__ br,      // [NH3] recurrent bias
    const bf16*  __restrict__ xp,      // [NM][NH3] bf16, row = t*NB + b
    const bf16*  __restrict__ h0bf,    // [B][H] bf16 h0, or null -> zeros
    bf16*        __restrict__ seq,     // [NT+1][B][H] bf16 (slots 1..NT written)
    const float* __restrict__ hf0,     // [B][H] fp32 h0, or null -> zeros
    float*       __restrict__ outBTH,  // layer2: d_out [B][T][H] fp32; else null
    float*       __restrict__ hfinal,  // [B][H] fp32 final-state sink
    unsigned*    __restrict__ cnt, unsigned tgtbase)
{
  __shared__ bf16  h_raw[16 * 520];    // h_prev [16 rows][512 k], row stride 520 (+16B pad)
  __shared__ float rec_l[16 * 388];    // [row][384 rec-cols + pad]
  __shared__ int   deadflag;
  int tid = threadIdx.x, lane = tid & 63, w = tid >> 6;   // 4 waves
  int g = blockIdx.x >> 2, c = blockIdx.x & 3;
  int bb0 = g * 16;
  int klane = (lane >> 4) * 8;
  if (tid == 0) deadflag = 0;

  // hoist Wu B-fragments + bias (loop-invariant): 6 tiles x 16 kt x bf16x8 = 384 VGPR
  bf16x8 wf[6][16];
  float  brv[6];
#pragma unroll
  for (int i = 0; i < 6; i++) {
    int lc = w*96 + i*16 + (lane & 15);            // local rec col 0..383
    int ng = (lc >> 7) * NH + c*128 + (lc & 127);  // global rec col (z/r/h thirds)
    brv[i] = br[ng];
    const bf16* wrow = wuT + (size_t)ng * NH + klane;
#pragma unroll
    for (int kt = 0; kt < 16; kt++) wf[i][kt] = *(const bf16x8*)(wrow + kt*32);
  }

  // gates ownership: thread -> (row, 8 consecutive h-cols); fp32 carry in registers
  int row = tid >> 4, jj = (tid & 15) * 8;
  int bb = bb0 + row, hc0 = c*128 + jj;
  float hreg[8];
#pragma unroll
  for (int q = 0; q < 8; q++)
    hreg[q] = hf0 ? hf0[(size_t)bb * NH + hc0 + q] : 0.0f;

  int chunk = tid & 15;                 // staging: thread covers k in [chunk*32, +32)
  bf16* lds_st = h_raw + row*520 + chunk*32;
  const char* abase = (const char*)h_raw + (lane & 15)*1040 + (lane >> 4)*16;
  float* rrow = rec_l + row*388;

  for (int t = 0; t < NT; t++) {
    // prefetch xp_t (independent of h -> overlaps the spin)
    const bf16* xrow = xp + ((size_t)t*NB + bb)*NH3 + c*128 + jj;
    u16x8 xz8 = *(const u16x8*)(xrow);
    u16x8 xr8 = *(const u16x8*)(xrow + 512);
    u16x8 xh8 = *(const u16x8*)(xrow + 1024);

    if (t > 0) {                        // wait for all 4 blocks of the group @ step t-1
      if (tid == 0) {
        unsigned tgt = tgtbase + 4u * (unsigned)t;
        long sp = 0;
        while (__hip_atomic_load(cnt + g, __ATOMIC_RELAXED, __HIP_MEMORY_SCOPE_AGENT) < tgt) {
          __builtin_amdgcn_s_sleep(1);
          if (++sp > (1L << 20)) { deadflag = 1; break; }
        }
      }
      __syncthreads();
      if (deadflag) return;
    }

    // stage h_prev [16x512] via device-coherent 8B loads (bypass stale L2)
    {
      const bf16* hs = (t == 0) ? h0bf : (seq + (size_t)t * NBH);
      if (hs == nullptr) {              // layer 0, t==0
#pragma unroll
        for (int j2 = 0; j2 < 8; j2++) *(unsigned long long*)(lds_st + j2*4) = 0ull;
      } else {
        const unsigned long long* gs =
            (const unsigned long long*)(hs + (size_t)bb * NH + chunk*32);
#pragma unroll
        for (int j2 = 0; j2 < 8; j2++)
          *(unsigned long long*)(lds_st + j2*4) =
              __hip_atomic_load(gs + j2, __ATOMIC_RELAXED, __HIP_MEMORY_SCOPE_AGENT);
      }
    }
    __syncthreads();

    // rec = h_prev @ Wu : 6 16x16 tiles per wave, K=512, weights in registers
    floatx4 acc[6];
#pragma unroll
    for (int i = 0; i < 6; i++) acc[i] = (floatx4){0.f, 0.f, 0.f, 0.f};
#pragma unroll
    for (int kt = 0; kt < 16; kt++) {
      bf16x8 ha = *(const bf16x8*)(abase + kt*64);
#pragma unroll
      for (int i = 0; i < 6; i++) acc[i] = mfma16(ha, wf[i][kt], acc[i]);
    }
    {
      int ccol = lane & 15, rb = (lane >> 4) * 4;
#pragma unroll
      for (int i = 0; i < 6; i++) {
        int lc0 = w*96 + i*16;
#pragma unroll
        for (int r = 0; r < 4; r++)
          rec_l[(rb + r)*388 + lc0 + ccol] = acc[i][r] + brv[i];  // bias folded here
      }
    }
    __syncthreads();

    // gates: 8 elements per thread, carry in registers
    {
      float4 rz0 = *(float4*)(rrow + jj),       rz1 = *(float4*)(rrow + jj + 4);
      float4 rr0 = *(float4*)(rrow + 128 + jj), rr1 = *(float4*)(rrow + 128 + jj + 4);
      float4 rh0 = *(float4*)(rrow + 256 + jj), rh1 = *(float4*)(rrow + 256 + jj + 4);
      float rz[8] = {rz0.x,rz0.y,rz0.z,rz0.w, rz1.x,rz1.y,rz1.z,rz1.w};
      float rr[8] = {rr0.x,rr0.y,rr0.z,rr0.w, rr1.x,rr1.y,rr1.z,rr1.w};
      float rh[8] = {rh0.x,rh0.y,rh0.z,rh0.w, rh1.x,rh1.y,rh1.z,rh1.w};
      unsigned short pk[8];
#pragma unroll
      for (int q = 0; q < 8; q++) {
        float z  = fsig(b2f(xz8[q]) + rz[q]);
        float r  = fsig(b2f(xr8[q]) + rr[q]);
        float hh = ftanh(b2f(xh8[q]) + r * rh[q]);
        float hn = z * hreg[q] + (1.0f - z) * hh;
        hreg[q] = hn;
        pk[q] = f2b(hn);
      }
      // publish h (write-through, device-coherent)
      bf16* so = seq + (size_t)(t+1) * NBH + (size_t)bb * NH + hc0;
      unsigned long long p0, p1;
      __builtin_memcpy(&p0, &pk[0], 8); __builtin_memcpy(&p1, &pk[4], 8);
      __hip_atomic_store((unsigned long long*)so,     p0, __ATOMIC_RELAXED, __HIP_MEMORY_SCOPE_AGENT);
      __hip_atomic_store((unsigned long long*)so + 1, p1, __ATOMIC_RELAXED, __HIP_MEMORY_SCOPE_AGENT);
      if (outBTH) {
        float* o = outBTH + ((size_t)bb * NT + t) * NH + hc0;
        *(float4*)o       = (float4){hreg[0], hreg[1], hreg[2], hreg[3]};
        *(float4*)(o + 4) = (float4){hreg[4], hreg[5], hreg[6], hreg[7]};
      }
      if (t == NT-1) {
        float* o = hfinal + (size_t)bb * NH + hc0;
        *(float4*)o       = (float4){hreg[0], hreg[1], hreg[2], hreg[3]};
        *(float4*)(o + 4) = (float4){hreg[4], hreg[5], hreg[6], hreg[7]};
      }
    }

    if (t < NT-1) {
      __syncthreads();                  // drains vmcnt(0): h stores at coherent point
      if (tid == 0)
        __hip_atomic_fetch_add(cnt + g, 1u, __ATOMIC_RELAXED, __HIP_MEMORY_SCOPE_AGENT);
    }
  }
}

extern "C" void kernel_launch(void* const* d_in, const int* in_sizes, int n_in,
                              void* d_out, int out_size, void* d_ws, size_t ws_size,
                              hipStream_t stream) {
  const float* x   = (const float*)d_in[0];
  const float* wk  = (const float*)d_in[1];
  const float* wu  = (const float*)d_in[2];
  const float* bis = (const float*)d_in[3];
  float* out = (float*)d_out;

  // workspace layout (same as round 2, ~137.4 MiB)
  const size_t REQ = 144048192;
  if (ws_size < REQ) {
    hipMemsetAsync(d_out, 0, (size_t)out_size * 4, stream);
    return;
  }
  char* ws = (char*)d_ws;
  bf16*  wkT   = (bf16*)(ws);
  bf16*  wuT   = (bf16*)(ws + 4718592);
  bf16*  xp    = (bf16*)(ws + 9437184);
  bf16*  seq   = (bf16*)(ws + 110100480);
  bf16*  xb    = seq;                          // alias: dead after layer-0 GEMM
  float* hlast = (float*)(ws + 143785984);
  unsigned* cnt = (unsigned*)(ws + 144048128);

  hipMemsetAsync(cnt, 0, 64, stream);
  transpose_cvt_kernel<<<dim3(48,16,3), dim3(32,8), 0, stream>>>(wk, wkT);
  transpose_cvt_kernel<<<dim3(48,16,3), dim3(32,8), 0, stream>>>(wu, wuT);
  cvt_x_kernel<<<(NM*NH/4)/256, 256, 0, stream>>>(x, xb);

  const size_t WS = (size_t)NH3 * NH;   // per-layer weight stride

  // layer 0
  gemm_xp_kernel<<<dim3(256,12), 256, 0, stream>>>(xb, wkT, bis + 0*2*NH3, xp, 0);
  gru_scan_kernel<<<32, 256, 0, stream>>>(wuT, bis + 0*2*NH3 + NH3, xp,
      nullptr, seq, nullptr, nullptr, hlast, cnt, 0u);
  // layer 1
  gemm_xp_kernel<<<dim3(256,12), 256, 0, stream>>>(seq + NBH, wkT + WS, bis + 1*2*NH3, xp, 1);
  gru_scan_kernel<<<32, 256, 0, stream>>>(wuT + WS, bis + 1*2*NH3 + NH3, xp,
      seq + (size_t)NT * NBH, seq, hlast, nullptr, hlast, cnt, 1020u);
  // layer 2: fp32 chain straight into d_out [B][T][H]; final state to d_out tail
  gemm_xp_kernel<<<dim3(256,12), 256, 0, stream>>>(seq + NBH, wkT + 2*WS, bis + 2*2*NH3, xp, 1);
  gru_scan_kernel<<<32, 256, 0, stream>>>(wuT + 2*WS, bis + 2*2*NH3 + NH3, xp,
      seq + (size_t)NT * NBH, seq, hlast, out, out + (size_t)NT * NBH, cnt, 2040u);

  (void)in_sizes; (void)n_in; (void)out_size; (void)ws_size;
}

// Round 6
// 3498.714 us; speedup vs baseline: 1.8002x; 1.1803x over previous
//
#include <hip/hip_runtime.h>
#include <hip/hip_bf16.h>

#define NL  3
#define NB  128
#define NT  256
#define NH  512
#define NH3 1536
#define NBH (NB*NH)      // 65536
#define NM  (NB*NT)      // 32768

typedef __bf16 bf16x8 __attribute__((ext_vector_type(8)));
typedef float  floatx4 __attribute__((ext_vector_type(4)));
typedef __hip_bfloat16 bf16;
typedef unsigned long long u64;

__device__ __forceinline__ floatx4 mfma16(bf16x8 a, bf16x8 b, floatx4 c) {
  return __builtin_amdgcn_mfma_f32_16x16x32_bf16(a, b, c, 0, 0, 0);
}
__device__ __forceinline__ void gload16(const void* g, void* l) {
  __builtin_amdgcn_global_load_lds(
      (const __attribute__((address_space(1))) unsigned int*)g,
      (__attribute__((address_space(3))) unsigned int*)l, 16, 0, 0);
}
__device__ __forceinline__ float fsig(float x)  { return 1.0f / (1.0f + __expf(-x)); }
__device__ __forceinline__ float ftanh(float x) { return 2.0f / (1.0f + __expf(-2.0f*x)) - 1.0f; }
__device__ __forceinline__ float b2f(unsigned short u) {
  unsigned v = (unsigned)u << 16; float f; __builtin_memcpy(&f, &v, 4); return f;
}
__device__ __forceinline__ unsigned short f2b(float f) {
  bf16 h = __float2bfloat16(f); unsigned short u; __builtin_memcpy(&u, &h, 2); return u;
}
__device__ __forceinline__ u64 ald(const u64* p) {
  return __hip_atomic_load(p, __ATOMIC_RELAXED, __HIP_MEMORY_SCOPE_AGENT);
}
__device__ __forceinline__ void ast(u64* p, u64 v) {
  __hip_atomic_store(p, v, __ATOMIC_RELAXED, __HIP_MEMORY_SCOPE_AGENT);
}

// ---------- transpose + cvt weights: fp32 [NL][NH][NH3] -> bf16 [NL][NH3][NH] ----------
__global__ void transpose_cvt_kernel(const float* __restrict__ in, bf16* __restrict__ out) {
  __shared__ float tile[32][33];
  int l = blockIdx.z;
  int n0 = blockIdx.x * 32, k0 = blockIdx.y * 32;
  const float* src = in + (size_t)l * NH * NH3;
  bf16* dst = out + (size_t)l * NH3 * NH;
  int tx = threadIdx.x, ty = threadIdx.y;    // 32 x 8
#pragma unroll
  for (int i = 0; i < 4; i++)
    tile[ty + 8*i][tx] = src[(size_t)(k0 + ty + 8*i) * NH3 + n0 + tx];
  __syncthreads();
#pragma unroll
  for (int i = 0; i < 4; i++)
    dst[(size_t)(n0 + ty + 8*i) * NH + k0 + tx] = __float2bfloat16(tile[tx][ty + 8*i]);
}

// ---------- elementwise fp32 -> bf16 (x input) ----------
__global__ void cvt_x_kernel(const float* __restrict__ in, bf16* __restrict__ out) {
  size_t i = (size_t)blockIdx.x * blockDim.x + threadIdx.x;
  float4 v = ((const float4*)in)[i];
  ushort4 pk;
  pk.x = f2b(v.x); pk.y = f2b(v.y); pk.z = f2b(v.z); pk.w = f2b(v.w);
  ((ushort4*)out)[i] = pk;
}

// ---------- xp GEMM (round-2 proven): C[m][n] = A[m]@Bt[n]^T + bias[n], bf16 out ----------
__global__ void __launch_bounds__(256, 2) gemm_xp_kernel(
    const bf16* __restrict__ A, const bf16* __restrict__ Bt,
    const float* __restrict__ bias, bf16* __restrict__ C, int a_mode)
{
  __shared__ char alds[16384];
  __shared__ char blds[16384];
  int tid = threadIdx.x;
  int lane = tid & 63, w = tid >> 6;
  int mblk = blockIdx.x, nblk = blockIdx.y;
  int wm = w >> 1, wn = w & 1;
  int klane = (lane >> 4) * 8;
  int r0 = 2*w*16 + (lane & 15);
  size_t arow0, arow1;
  if (a_mode == 0) {
    arow0 = ((size_t)r0 * NT + mblk) * NH;
    arow1 = ((size_t)(r0 + 16) * NT + mblk) * NH;
  } else {
    arow0 = (size_t)(mblk*128 + r0) * NH;
    arow1 = arow0 + (size_t)16 * NH;
  }
  size_t brow0 = (size_t)(nblk*128 + 2*w*16 + (lane & 15)) * NH;
  size_t brow1 = brow0 + (size_t)16 * NH;

  floatx4 acc[4][4];
#pragma unroll
  for (int i = 0; i < 4; i++)
#pragma unroll
    for (int j = 0; j < 4; j++) acc[i][j] = (floatx4){0.f, 0.f, 0.f, 0.f};

  for (int kk = 0; kk < 8; kk++) {
    int kb = kk*64 + klane;
#pragma unroll
    for (int kt = 0; kt < 2; kt++) {
      int kg = kb + kt*32;
      gload16(A  + arow0 + kg, alds + (kt*8 + 2*w    ) * 1024);
      gload16(A  + arow1 + kg, alds + (kt*8 + 2*w + 1) * 1024);
      gload16(Bt + brow0 + kg, blds + (kt*8 + 2*w    ) * 1024);
      gload16(Bt + brow1 + kg, blds + (kt*8 + 2*w + 1) * 1024);
    }
    __syncthreads();
#pragma unroll
    for (int kt = 0; kt < 2; kt++) {
      bf16x8 af[4], bfr[4];
#pragma unroll
      for (int i = 0; i < 4; i++) af[i]  = *(const bf16x8*)(alds + ((kt*8 + wm*4 + i)*64 + lane)*16);
#pragma unroll
      for (int j = 0; j < 4; j++) bfr[j] = *(const bf16x8*)(blds + ((kt*8 + wn*4 + j)*64 + lane)*16);
#pragma unroll
      for (int i = 0; i < 4; i++)
#pragma unroll
        for (int j = 0; j < 4; j++)
          acc[i][j] = mfma16(af[i], bfr[j], acc[i][j]);
    }
    __syncthreads();
  }
  int cl = lane & 15, rbase = (lane >> 4) * 4;
#pragma unroll
  for (int i = 0; i < 4; i++) {
    int gm = mblk*128 + wm*64 + i*16 + rbase;
#pragma unroll
    for (int j = 0; j < 4; j++) {
      int gn = nblk*128 + wn*64 + j*16 + cl;
      float bv = bias[gn];
#pragma unroll
      for (int r = 0; r < 4; r++)
        C[(size_t)(gm + r) * NH3 + gn] = __float2bfloat16(acc[i][j][r] + bv);
    }
  }
}

// =====================================================================================
// gru_scan: 32 blocks = 8 groups x 4 col-blocks, 512 thr (8 waves, 2/SIMD -> 256-VGPR cap).
// Block (g,c): 16 batch rows x 384 rec-cols ({z,r,h} x h-cols [c*128..+128)).
// Weights hoisted: wf[3][16] bf16x8 = 192 VGPR, loop-invariant (fits — no spills).
// Swapped MFMA: D[m=rec-col][n=batch row]; lane owns (row=lane&15, 4 cols) for all gates
// -> gates fully in registers, no rec_l, no bank conflicts (all LDS lane-linear 16B).
// ONE runtime protocol (round-3 replay-proven): per-group 4-sibling lockstep counter;
// h published/consumed via 8B relaxed-agent atomics on seq slots. xp read with plain
// loads (written by a previous kernel — dispatch-boundary coherence, round-2 proven).
// =====================================================================================
__global__ void __launch_bounds__(512, 2) gru_scan_kernel(
    const bf16*  __restrict__ wuT,   // [NH3][NH] bf16 (this layer)
    const float* __restrict__ br,    // [NH3] recurrent bias
    const bf16*  __restrict__ xp,    // [NM][NH3] bf16, row = t*NB + b (bias folded)
    bf16*        __restrict__ seq,   // [NT+1][B][H] bf16; slot 256 on entry = prev layer h_255
    float*       __restrict__ hlast, // [B][H] fp32 carry handoff (in: prev layer, out: ours)
    float*       __restrict__ out,   // layer2: d_out; else null
    unsigned*    __restrict__ cnt,   // 8 group counters (monotonic across layers)
    unsigned tgtbase, int layer)
{
  __shared__ __align__(16) char h_raw[16384];   // B-frags: [kt(16)][lane(64)]*16B
  __shared__ int deadflag;
  int tid = threadIdx.x, lane = tid & 63, w = tid >> 6;   // 8 waves
  int g = blockIdx.x >> 2, c = blockIdx.x & 3;
  int bb0 = g * 16;
  int r16 = lane & 15, h4 = lane >> 4;
  int srow = tid & 15, ssc = tid >> 4;                    // staging (row, chunk)
  if (tid == 0) deadflag = 0;

  // ---- hoist weight A-fragments (loop-invariant): 3 x 16 x bf16x8 = 192 VGPR ----
  bf16x8 wf[3][16];
  float  bv[3][4];
#pragma unroll
  for (int G = 0; G < 3; G++) {
    const bf16* wrow = wuT + ((size_t)(G*NH + c*128 + w*16 + r16)) * NH + h4*8;
#pragma unroll
    for (int kt = 0; kt < 16; kt++) wf[G][kt] = *(const bf16x8*)(wrow + kt*32);
#pragma unroll
    for (int q = 0; q < 4; q++) bv[G][q] = br[G*NH + c*128 + w*16 + h4*4 + q];
  }

  // ---- fp32 carry: this lane's 4 h-elements (row r16, cols c*128+w*16+h4*4..+4) ----
  float hreg[4];
  if (layer == 0) {
    hreg[0] = hreg[1] = hreg[2] = hreg[3] = 0.0f;
  } else {
    const float* hsrc = hlast + (size_t)(bb0 + r16) * NH + c*128 + w*16 + h4*4;
    float4 v = *(const float4*)hsrc;          // prev kernel's output: plain load OK
    hreg[0] = v.x; hreg[1] = v.y; hreg[2] = v.z; hreg[3] = v.w;
  }

  u64* seqU = (u64*)seq;

  for (int t = 0; t < NT; t++) {
    // prefetch xp_t for this lane (plain loads; xp written by an earlier dispatch)
    const u64* xq = (const u64*)(xp + ((size_t)t*NB + bb0 + r16)*NH3 + c*128 + w*16 + h4*4);
    u64 xv0 = xq[0], xv1 = xq[128], xv2 = xq[256];   // gates 512 cols (=128 u64) apart

    if (t > 0) {   // lockstep: siblings finished step t-1 (their publish drained)
      if (tid == 0) {
        unsigned tgt = tgtbase + 4u * (unsigned)t;
        long sp = 0;
        while (__hip_atomic_load(cnt + g, __ATOMIC_RELAXED, __HIP_MEMORY_SCOPE_AGENT) < tgt) {
          __builtin_amdgcn_s_sleep(1);
          if (++sp > (1L << 22)) { deadflag = 1; break; }
        }
      }
      __syncthreads();                 // release all waves; deadflag visible
      if (deadflag) return;
    }

    // ---- stage h_prev [16x512] into B-fragment layout (device-coherent 8B loads) ----
    if (layer == 0 && t == 0) {
      *(int4*)(h_raw + tid*32)      = (int4){0,0,0,0};
      *(int4*)(h_raw + tid*32 + 16) = (int4){0,0,0,0};
    } else {
      int slot = (t == 0) ? NT : t;    // t==0: prev layer's h_255 lives in slot 256
      const u64* src = seqU + ((size_t)slot*NBH + (size_t)(bb0 + srow)*NH) / 4;
#pragma unroll
      for (int d = 0; d < 2; d++) {
        int sc = ssc + d*32;           // 16B chunk sc of row srow: k = sc*8..+8
        u64 q0 = ald(src + sc*2), q1 = ald(src + sc*2 + 1);
        u64* dst = (u64*)(h_raw + (((sc >> 2)*64) + (sc & 3)*16 + srow)*16);
        dst[0] = q0; dst[1] = q1;
      }
    }
    __syncthreads();                   // staging visible to all waves

    // ---- rec^T = Wu_cols x h : 3 tiles/wave, K=512, weights in registers ----
    floatx4 ac0 = (floatx4){0,0,0,0}, ac1 = (floatx4){0,0,0,0}, ac2 = (floatx4){0,0,0,0};
#pragma unroll
    for (int kt = 0; kt < 16; kt++) {
      bf16x8 hb = *(const bf16x8*)(h_raw + (kt*64 + lane)*16);
      ac0 = mfma16(wf[0][kt], hb, ac0);
      ac1 = mfma16(wf[1][kt], hb, ac1);
      ac2 = mfma16(wf[2][kt], hb, ac2);
    }

    // ---- gates in registers ----
    unsigned short pk[4];
#pragma unroll
    for (int q = 0; q < 4; q++) {
      float rz = ac0[q] + bv[0][q];
      float rr = ac1[q] + bv[1][q];
      float rh = ac2[q] + bv[2][q];
      float xz = b2f((unsigned short)(xv0 >> (16*q)));
      float xr = b2f((unsigned short)(xv1 >> (16*q)));
      float xh = b2f((unsigned short)(xv2 >> (16*q)));
      float z  = fsig(xz + rz);
      float r  = fsig(xr + rr);
      float hh = ftanh(xh + r * rh);
      float hn = z * hreg[q] + (1.0f - z) * hh;
      hreg[q] = hn;
      pk[q] = f2b(hn);
    }
    u64 pv; __builtin_memcpy(&pv, pk, 8);
    // publish h_t -> seq slot t+1 (device-coherent)
    ast(seqU + ((size_t)(t+1)*NBH + (size_t)(bb0 + r16)*NH)/4 + c*32 + w*4 + h4, pv);

    if (layer == 2) {                  // fp32 chain straight into d_out [B][T][H] flat
      float* o = out + ((size_t)(bb0 + r16)*NT + t)*NH + c*128 + w*16 + h4*4;
      *(float4*)o = (float4){hreg[0], hreg[1], hreg[2], hreg[3]};
      if (t == NT - 1) {               // final state tail [B][H]
        float* o2 = out + (size_t)NM*NH + (size_t)(bb0 + r16)*NH + c*128 + w*16 + h4*4;
        *(float4*)o2 = (float4){hreg[0], hreg[1], hreg[2], hreg[3]};
      }
    } else if (t == NT - 1) {          // fp32 carry handoff for next layer (plain store)
      float* o = hlast + (size_t)(bb0 + r16)*NH + c*128 + w*16 + h4*4;
      *(float4*)o = (float4){hreg[0], hreg[1], hreg[2], hreg[3]};
    }

    __syncthreads();                   // drain: publish complete at coherent point
    if (tid == 0 && t < NT - 1)
      __hip_atomic_fetch_add(cnt + g, 1u, __ATOMIC_RELAXED, __HIP_MEMORY_SCOPE_AGENT);
  }
}

extern "C" void kernel_launch(void* const* d_in, const int* in_sizes, int n_in,
                              void* d_out, int out_size, void* d_ws, size_t ws_size,
                              hipStream_t stream) {
  const float* x   = (const float*)d_in[0];
  const float* wk  = (const float*)d_in[1];
  const float* wu  = (const float*)d_in[2];
  const float* bis = (const float*)d_in[3];
  float* out = (float*)d_out;

  // workspace layout — identical to round 2/3 (proven to fit):
  //   wkT   @ 0            4,718,592   [3][1536][512] bf16
  //   wuT   @ 4,718,592    4,718,592
  //   xp    @ 9,437,184  100,663,296   [32768][1536] bf16
  //   seq   @ 110,100,480 33,685,504   [257][128][512] bf16 (xb aliases base)
  //   hlast @ 143,785,984    262,144   [128][512] fp32
  //   cnt   @ 144,048,128         64   8 x u32
  const size_t REQ = 144048192;
  if (ws_size < REQ) {
    hipMemsetAsync(d_out, 0, (size_t)out_size * 4, stream);
    return;
  }
  char* ws = (char*)d_ws;
  bf16*  wkT   = (bf16*)(ws);
  bf16*  wuT   = (bf16*)(ws + 4718592);
  bf16*  xp    = (bf16*)(ws + 9437184);
  bf16*  seq   = (bf16*)(ws + 110100480);
  bf16*  xb    = seq;                          // alias: dead after layer-0 GEMM
  float* hlast = (float*)(ws + 143785984);
  unsigned* cnt = (unsigned*)(ws + 144048128);

  hipMemsetAsync(cnt, 0, 64, stream);
  transpose_cvt_kernel<<<dim3(48,16,3), dim3(32,8), 0, stream>>>(wk, wkT);
  transpose_cvt_kernel<<<dim3(48,16,3), dim3(32,8), 0, stream>>>(wu, wuT);
  cvt_x_kernel<<<(NM*NH/4)/256, 256, 0, stream>>>(x, xb);

  const size_t WS = (size_t)NH3 * NH;   // per-layer weight stride

  // layer 0
  gemm_xp_kernel<<<dim3(256,12), 256, 0, stream>>>(xb, wkT, bis + 0*2*NH3, xp, 0);
  gru_scan_kernel<<<32, 512, 0, stream>>>(wuT, bis + 0*2*NH3 + NH3, xp,
      seq, hlast, nullptr, cnt, 0u, 0);
  // layer 1 (gemm reads seq slots 1..256 = layer-0 h)
  gemm_xp_kernel<<<dim3(256,12), 256, 0, stream>>>(seq + NBH, wkT + WS, bis + 1*2*NH3, xp, 1);
  gru_scan_kernel<<<32, 512, 0, stream>>>(wuT + WS, bis + 1*2*NH3 + NH3, xp,
      seq, hlast, nullptr, cnt, 1020u, 1);
  // layer 2 (fp32 chain straight into d_out)
  gemm_xp_kernel<<<dim3(256,12), 256, 0, stream>>>(seq + NBH, wkT + 2*WS, bis + 2*2*NH3, xp, 1);
  gru_scan_kernel<<<32, 512, 0, stream>>>(wuT + 2*WS, bis + 2*2*NH3 + NH3, xp,
      seq, hlast, out, cnt, 2040u, 2);

  (void)in_sizes; (void)n_in; (void)out_size; (void)ws_size;
}